// Round 8
// baseline (224.265 us; speedup 1.0000x reference)
//
#include <hip/hip_runtime.h>
#include <hip/hip_bf16.h>

#define BATCH   2
#define L_SEQ   2048
#define DMODEL  1024
#define NHEADS  16
#define DHEAD   64
#define SEG     (BATCH*NHEADS*L_SEQ*DHEAD)   // 4,194,304 elements per q/k/v segment

typedef __attribute__((ext_vector_type(8)))  short bf16x8;
typedef __attribute__((ext_vector_type(4)))  float f32x4;
typedef __attribute__((ext_vector_type(16))) float f32x16;

__device__ __forceinline__ unsigned short f2b(float f) {
    unsigned int u = __float_as_uint(f);
    return (unsigned short)((u + 0x7FFFu + ((u >> 16) & 1u)) >> 16);   // RNE
}
__device__ __forceinline__ unsigned int pk2(float a, float b) {
    __hip_bfloat162 h = __float22bfloat162_rn(make_float2(a, b));
    return *(unsigned int*)&h;
}
__device__ __forceinline__ void glds16(const unsigned short* g, unsigned short* l) {
    __builtin_amdgcn_global_load_lds(
        (const __attribute__((address_space(1))) unsigned int*)g,
        (__attribute__((address_space(3))) unsigned int*)l, 16, 0, 0);
}

// ---------------------------------------------------------------------------
// prep: transpose-cast weights only. 1024 blocks: 0..767 w_qkv, 768..1023 w_proj.
// ---------------------------------------------------------------------------
__device__ __forceinline__ void tcast64(const float* __restrict__ in,
                                        unsigned short* __restrict__ out,
                                        int K, int N, int bx, int by, int t) {
    __shared__ unsigned short T[64][65];
    const int k0 = by * 64, n0 = bx * 64;
    const int r = t >> 4, c4 = (t & 15) * 4;
#pragma unroll
    for (int rep = 0; rep < 4; ++rep) {
        int kk = rep * 16 + r;
        float4 f = *(const float4*)&in[(size_t)(k0 + kk) * N + n0 + c4];
        T[kk][c4 + 0] = f2b(f.x);
        T[kk][c4 + 1] = f2b(f.y);
        T[kk][c4 + 2] = f2b(f.z);
        T[kk][c4 + 3] = f2b(f.w);
    }
    __syncthreads();
#pragma unroll
    for (int rep = 0; rep < 4; ++rep) {
        int nn = rep * 16 + r;
        ushort4 o;
        o.x = T[c4 + 0][nn];
        o.y = T[c4 + 1][nn];
        o.z = T[c4 + 2][nn];
        o.w = T[c4 + 3][nn];
        *(ushort4*)&out[(size_t)(n0 + nn) * K + k0 + c4] = o;
    }
}

__global__ __launch_bounds__(256)
void prep(const float* __restrict__ wqkv, const float* __restrict__ wproj,
          unsigned short* __restrict__ wqkvT, unsigned short* __restrict__ wprojT) {
    const int id = blockIdx.x, t = threadIdx.x;
    if (id < 768) {
        tcast64(wqkv, wqkvT, DMODEL, 3 * DMODEL, id % 48, id / 48, t);
    } else {
        int lid = id - 768;
        tcast64(wproj, wprojT, DMODEL, DMODEL, lid & 15, lid >> 4, t);
    }
}

// ---------------------------------------------------------------------------
// QKV GEMM: C = cast_bf16(x)[4096,1024] @ wqkvT[3072,1024]^T, fused cast.
// 128x128 tile, BK=64. A: fp32 register prefetch + in-reg cvt -> LDS.
// B: glds16 with XOR source-chunk swizzle. Epilogue: acc -> swizzled 32KB
// LDS tile -> coalesced 16B stores. n0<2048: Q/K [bh][l][d] (Q scaled
// 0.125*log2e). n0>=2048: operand-swapped MFMAs -> V^T [bh][d][L].
// NOTE (r7 bug fix): for vrole, acc[i][j][r] = (feature = wn+j*16+quad*4+r,
// token = wm+i*16+l16) — the LDS-tile write must use that mapping.
// ---------------------------------------------------------------------------
__global__ __launch_bounds__(256)
void gemm_qkv(const float* __restrict__ X, const unsigned short* __restrict__ Bt,
              unsigned short* __restrict__ Cb) {
    __shared__ unsigned short SLDS[128 * 128];   // 32 KB: A(16K) + B(16K), then epilogue
    unsigned short* Asm = SLDS;
    unsigned short* Bsm = SLDS + 128 * 64;

    const int t = threadIdx.x;
    const int lane = t & 63, wave = t >> 6;
    const int quad = lane >> 4, l16 = lane & 15;
    const int wm = (wave >> 1) * 64, wn = (wave & 1) * 64;
    const int m0 = blockIdx.y * 128, n0 = blockIdx.x * 128;
    const bool vrole = (n0 >= 2048);

    // staging ids: row_local = wave*32 + i*8 + (lane>>3), chunk = lane&7
    const int srl = lane >> 3, sc = lane & 7;
    const int gsw = sc ^ srl;   // B source-chunk swizzle (dest is lane-linear)
    const float* gax[4];
    const unsigned short* gbp[4];
    unsigned short* lb[4];
    int lA[4];
#pragma unroll
    for (int i = 0; i < 4; ++i) {
        int row = wave * 32 + i * 8 + srl;
        gax[i] = &X[(size_t)(m0 + row) * DMODEL + sc * 8];
        gbp[i] = &Bt[(size_t)(n0 + row) * DMODEL + gsw * 8];
        lA[i]  = row * 64 + ((sc ^ srl) * 8);
        lb[i]  = &Bsm[(wave * 32 + i * 8) * 64];
    }
    const int sx = l16 & 7;

    f32x4 acc[4][4];
#pragma unroll
    for (int i = 0; i < 4; ++i)
#pragma unroll
        for (int j = 0; j < 4; ++j)
#pragma unroll
            for (int r = 0; r < 4; ++r) acc[i][j][r] = 0.0f;

    float4 a0[4], a1[4];
#pragma unroll
    for (int i = 0; i < 4; ++i) {
        a0[i] = *(const float4*)(gax[i]);
        a1[i] = *(const float4*)(gax[i] + 4);
    }

    for (int k0 = 0; k0 < DMODEL; k0 += 64) {
        __syncthreads();   // prior frag reads done
#pragma unroll
        for (int i = 0; i < 4; ++i) {
            uint4 w = make_uint4(pk2(a0[i].x, a0[i].y), pk2(a0[i].z, a0[i].w),
                                 pk2(a1[i].x, a1[i].y), pk2(a1[i].z, a1[i].w));
            *(uint4*)&Asm[lA[i]] = w;
            glds16(gbp[i] + k0, lb[i]);
        }
        if (k0 + 64 < DMODEL) {
#pragma unroll
            for (int i = 0; i < 4; ++i) {
                a0[i] = *(const float4*)(gax[i] + k0 + 64);
                a1[i] = *(const float4*)(gax[i] + k0 + 68);
            }
        }
        __syncthreads();   // drains glds vmcnt + lgkm
#pragma unroll
        for (int s = 0; s < 2; ++s) {
            bf16x8 af[4], bfr[4];
#pragma unroll
            for (int i = 0; i < 4; ++i)
                af[i] = *(const bf16x8*)&Asm[(wm + i * 16 + l16) * 64 + ((4 * s + quad) ^ sx) * 8];
#pragma unroll
            for (int j = 0; j < 4; ++j)
                bfr[j] = *(const bf16x8*)&Bsm[(wn + j * 16 + l16) * 64 + ((4 * s + quad) ^ sx) * 8];
            if (!vrole) {
#pragma unroll
                for (int i = 0; i < 4; ++i)
#pragma unroll
                    for (int j = 0; j < 4; ++j)
                        acc[i][j] = __builtin_amdgcn_mfma_f32_16x16x32_bf16(af[i], bfr[j], acc[i][j], 0, 0, 0);
            } else {   // C^T: rows=features, cols=tokens
#pragma unroll
                for (int i = 0; i < 4; ++i)
#pragma unroll
                    for (int j = 0; j < 4; ++j)
                        acc[i][j] = __builtin_amdgcn_mfma_f32_16x16x32_bf16(bfr[j], af[i], acc[i][j], 0, 0, 0);
            }
        }
    }

    // ---- epilogue: acc -> swizzled LDS tile [128][128] -> coalesced stores
    const float qscale = 0.1803368801111244f;   // 0.125 * log2(e)
    const float scl = (!vrole && n0 < 1024) ? qscale : 1.0f;
    __syncthreads();   // all frag reads done before overwriting SLDS
#pragma unroll
    for (int i = 0; i < 4; ++i)
#pragma unroll
        for (int r = 0; r < 4; ++r) {
#pragma unroll
            for (int j = 0; j < 4; ++j) {
                int row_l, col_l;
                if (!vrole) {            // [token][feature]
                    row_l = wm + i * 16 + quad * 4 + r;
                    col_l = wn + j * 16 + l16;
                } else {                 // [feature][token] (acc is C^T)
                    row_l = wn + j * 16 + quad * 4 + r;
                    col_l = wm + i * 16 + l16;
                }
                int key = row_l & 7;
                SLDS[row_l * 128 + (((col_l >> 3) ^ key) * 8) + (col_l & 7)] =
                    f2b(acc[i][j][r] * scl);
            }
        }
    __syncthreads();

    const int s0 = n0 >> 10;        // 0=Q, 1=K (vrole handled separately)
    const int bb = m0 >> 11;        // batch index (tile never crosses)
#pragma unroll
    for (int it = 0; it < 4; ++it) {
        int row = it * 32 + (t >> 3);
        int c = t & 7;
        int key = row & 7;
        bf16x8 v0 = *(const bf16x8*)&SLDS[row * 128 + ((c ^ key) * 8)];
        bf16x8 v1 = *(const bf16x8*)&SLDS[row * 128 + (((c + 8) ^ key) * 8)];
        if (!vrole) {
            int token = m0 + row, lp = token & (L_SEQ - 1);
            int n_a = n0 + c * 8,        h_a = (n_a >> 6) & 15, d_a = n_a & 63;
            int n_b = n0 + (c + 8) * 8,  h_b = (n_b >> 6) & 15, d_b = n_b & 63;
            size_t base = (size_t)s0 * SEG;
            *(bf16x8*)&Cb[base + (((size_t)(bb * NHEADS + h_a) * L_SEQ + lp) * DHEAD) + d_a] = v0;
            *(bf16x8*)&Cb[base + (((size_t)(bb * NHEADS + h_b) * L_SEQ + lp) * DHEAD) + d_b] = v1;
        } else {
            int fr = (n0 - 2048) + row;
            int h = fr >> 6, dd = fr & 63;
            int lp0 = (m0 & (L_SEQ - 1));
            size_t base = 2 * (size_t)SEG +
                          (((size_t)(bb * NHEADS + h) * DHEAD + dd) * L_SEQ) + lp0;
            *(bf16x8*)&Cb[base + c * 8]       = v0;
            *(bf16x8*)&Cb[base + (c + 8) * 8] = v1;
        }
    }
}

// ---------------------------------------------------------------------------
// proj GEMM: out = ao[4096,1024] @ wprojT[1024,1024]^T, fp32 store.
// ---------------------------------------------------------------------------
__global__ __launch_bounds__(256)
void gemm_proj(const unsigned short* __restrict__ A, const unsigned short* __restrict__ Bt,
               float* __restrict__ Cf) {
    __shared__ unsigned short Asm[128 * 64];
    __shared__ unsigned short Bsm[128 * 64];

    const int t = threadIdx.x;
    const int lane = t & 63, wave = t >> 6;
    const int quad = lane >> 4, l16 = lane & 15;
    const int wm = (wave >> 1) * 64, wn = (wave & 1) * 64;
    const int m0 = blockIdx.y * 128, n0 = blockIdx.x * 128;
    const int K = DMODEL, N = DMODEL;

    const int gsw = (lane & 7) ^ (lane >> 3);
    const unsigned short* ga[4];
    const unsigned short* gb[4];
    unsigned short* la[4];
    unsigned short* lb[4];
#pragma unroll
    for (int i = 0; i < 4; ++i) {
        int row = wave * 32 + i * 8 + (lane >> 3);
        ga[i] = &A[(size_t)(m0 + row) * K + gsw * 8];
        gb[i] = &Bt[(size_t)(n0 + row) * K + gsw * 8];
        la[i] = &Asm[(wave * 32 + i * 8) * 64];
        lb[i] = &Bsm[(wave * 32 + i * 8) * 64];
    }
    const int sx = l16 & 7;

    f32x4 acc[4][4];
#pragma unroll
    for (int i = 0; i < 4; ++i)
#pragma unroll
        for (int j = 0; j < 4; ++j)
#pragma unroll
            for (int r = 0; r < 4; ++r) acc[i][j][r] = 0.0f;

    for (int k0 = 0; k0 < K; k0 += 64) {
        __syncthreads();
#pragma unroll
        for (int i = 0; i < 4; ++i) {
            glds16(ga[i] + k0, la[i]);
            glds16(gb[i] + k0, lb[i]);
        }
        __syncthreads();
#pragma unroll
        for (int s = 0; s < 2; ++s) {
            bf16x8 af[4], bfr[4];
#pragma unroll
            for (int i = 0; i < 4; ++i)
                af[i] = *(const bf16x8*)&Asm[(wm + i * 16 + l16) * 64 + ((4 * s + quad) ^ sx) * 8];
#pragma unroll
            for (int j = 0; j < 4; ++j)
                bfr[j] = *(const bf16x8*)&Bsm[(wn + j * 16 + l16) * 64 + ((4 * s + quad) ^ sx) * 8];
#pragma unroll
            for (int i = 0; i < 4; ++i)
#pragma unroll
                for (int j = 0; j < 4; ++j)
                    acc[i][j] = __builtin_amdgcn_mfma_f32_16x16x32_bf16(af[i], bfr[j], acc[i][j], 0, 0, 0);
        }
    }

#pragma unroll
    for (int i = 0; i < 4; ++i)
#pragma unroll
        for (int r = 0; r < 4; ++r) {
            int row = m0 + wm + i * 16 + quad * 4 + r;
#pragma unroll
            for (int j = 0; j < 4; ++j)
                Cf[(size_t)row * N + n0 + wn + j * 16 + l16] = acc[i][j][r];
        }
}

// ---------------------------------------------------------------------------
// Flash causal attention, 32x32x16 MFMA, S^T form, FIXED-max softmax (m=0).
// 512 UNIFORM blocks: block (p,bh) runs q-tiles 31-p then p = 17 strips
// exactly -> no tail. 4 waves: qhalf = w&1 (32 q), kpar = w>>1 (64-key half
// of each 128-key strip). Chunked XOR LDS, register prefetch (incl. across
// the half boundary). kp=1 waves merge O/rs into kp=0 via LDS per half.
// ---------------------------------------------------------------------------
__global__ __launch_bounds__(256)
void attn_mfma(const unsigned short* __restrict__ Qg, const unsigned short* __restrict__ Kg,
               const unsigned short* __restrict__ Vg, unsigned short* __restrict__ Ao) {
    __shared__ unsigned short Ksm[128 * 64];
    __shared__ unsigned short Vsm[64 * 128];
    __shared__ unsigned short Psm[4 * 32 * 64];

    const int t = threadIdx.x;
    const int lane = t & 63, wave = t >> 6;
    const int l31 = lane & 31, hi = lane >> 5;
    const int bh = blockIdx.x & 31, p = blockIdx.x >> 5;   // p = 0..15
    const int qh = wave & 1, kp = wave >> 1;
    const int b = bh >> 4, h = bh & 15;
    const size_t qkbase = (size_t)bh * L_SEQ * DHEAD;
    const size_t vbase  = (size_t)bh * DHEAD * L_SEQ;

    const int kc0 = t & 7,  kr0 = (t >> 3) * 4;
    const int vc0 = t & 15, vd0 = (t >> 4) * 4;
    unsigned short* Pw = Psm + wave * 32 * 64;

    bf16x8 gk[4], gv[4];
#pragma unroll
    for (int i = 0; i < 4; ++i) {
        gk[i] = *(const bf16x8*)&Kg[qkbase + (size_t)(kr0 + i) * DHEAD + kc0 * 8];
        gv[i] = *(const bf16x8*)&Vg[vbase + (size_t)(vd0 + i) * L_SEQ + vc0 * 8];
    }

#pragma unroll
    for (int half = 0; half < 2; ++half) {
        const int Qt = (half == 0) ? (31 - p) : p;
        const int wq0 = Qt * 64 + qh * 32;
        const int nstrip = (Qt >> 1) + 1;

        bf16x8 bq[4];
#pragma unroll
        for (int ks = 0; ks < 4; ++ks)
            bq[ks] = *(const bf16x8*)&Qg[qkbase + (size_t)(wq0 + l31) * DHEAD + ks * 16 + hi * 8];

        f32x16 O0, O1;
#pragma unroll
        for (int r = 0; r < 16; ++r) { O0[r] = 0.0f; O1[r] = 0.0f; }
        float rs = 0.0f;

        for (int s = 0; s < nstrip; ++s) {
            __syncthreads();
#pragma unroll
            for (int i = 0; i < 4; ++i) {
                *(bf16x8*)&Ksm[(kc0 * 128 + ((kr0 + i) ^ kc0)) * 8] = gk[i];
                *(bf16x8*)&Vsm[(vc0 * 64 + ((vd0 + i) ^ vc0)) * 8] = gv[i];
            }
            if (s + 1 < nstrip || half == 0) {
                const int kn = (s + 1 < nstrip) ? (s + 1) * 128 : 0;
#pragma unroll
                for (int i = 0; i < 4; ++i) {
                    gk[i] = *(const bf16x8*)&Kg[qkbase + (size_t)(kn + kr0 + i) * DHEAD + kc0 * 8];
                    gv[i] = *(const bf16x8*)&Vg[vbase + (size_t)(vd0 + i) * L_SEQ + kn + vc0 * 8];
                }
            }
            __syncthreads();

            const int keybase = s * 128 + kp * 64;
            if (keybase <= wq0 + 31) {
                f32x16 ST[2];
#pragma unroll
                for (int kh = 0; kh < 2; ++kh) {
#pragma unroll
                    for (int r = 0; r < 16; ++r) ST[kh][r] = 0.0f;
#pragma unroll
                    for (int ks = 0; ks < 4; ++ks) {
                        const int c = ks * 2 + hi;
                        const int rk = kp * 64 + kh * 32 + l31;
                        bf16x8 a = *(const bf16x8*)&Ksm[(c * 128 + (rk ^ c)) * 8];
                        ST[kh] = __builtin_amdgcn_mfma_f32_32x32x16_bf16(a, bq[ks], ST[kh], 0, 0, 0);
                    }
                }

                if (keybase + 63 > wq0) {   // diagonal: causal mask
                    const int qg = wq0 + l31;
#pragma unroll
                    for (int kh = 0; kh < 2; ++kh)
#pragma unroll
                        for (int r = 0; r < 16; ++r) {
                            int keyg = keybase + kh * 32 + (r & 3) + 8 * (r >> 2) + 4 * hi;
                            if (keyg > qg) ST[kh][r] = -1e30f;
                        }
                }

#pragma unroll
                for (int kh = 0; kh < 2; ++kh)
#pragma unroll
                    for (int g = 0; g < 4; ++g) {
                        float p0 = __builtin_amdgcn_exp2f(ST[kh][4 * g + 0]);
                        float p1 = __builtin_amdgcn_exp2f(ST[kh][4 * g + 1]);
                        float p2 = __builtin_amdgcn_exp2f(ST[kh][4 * g + 2]);
                        float p3 = __builtin_amdgcn_exp2f(ST[kh][4 * g + 3]);
                        rs += (p0 + p1) + (p2 + p3);
                        const int c = kh * 4 + g;
                        *(uint2*)&Pw[(c * 32 + (l31 ^ c)) * 8 + hi * 4] =
                            make_uint2(pk2(p0, p1), pk2(p2, p3));
                    }

#pragma unroll
                for (int ks = 0; ks < 4; ++ks) {
                    const int cp = ks * 2 + hi;
                    const int cv = kp * 8 + ks * 2 + hi;
                    bf16x8 pa = *(const bf16x8*)&Pw[(cp * 32 + (l31 ^ cp)) * 8];
                    bf16x8 v0 = *(const bf16x8*)&Vsm[(cv * 64 + (l31 ^ cv)) * 8];
                    bf16x8 v1 = *(const bf16x8*)&Vsm[(cv * 64 + ((32 + l31) ^ cv)) * 8];
                    O0 = __builtin_amdgcn_mfma_f32_32x32x16_bf16(pa, v0, O0, 0, 0, 0);
                    O1 = __builtin_amdgcn_mfma_f32_32x32x16_bf16(pa, v1, O1, 0, 0, 0);
                }
            }
        }

        rs += __shfl_xor(rs, 32, 64);

        // merge key-parities via LDS (Ksm/Vsm reused as scratch)
        __syncthreads();
        float* Oex = (float*)Ksm;
        float* Rex = (float*)Vsm;
        if (kp == 1) {
#pragma unroll
            for (int r = 0; r < 16; ++r) {
                int qloc = (r & 3) + 8 * (r >> 2) + 4 * hi;
                Oex[qh * 2048 + qloc * 64 + l31]      = O0[r];
                Oex[qh * 2048 + qloc * 64 + 32 + l31] = O1[r];
            }
            if (hi == 0) Rex[qh * 32 + l31] = rs;
        }
        __syncthreads();
        if (kp == 0) {
            float rs_tot = rs + Rex[qh * 32 + l31];
            float linv = 1.0f / rs_tot;
            float lf[16];
#pragma unroll
            for (int r = 0; r < 16; ++r) {
                int qloc = (r & 3) + 8 * (r >> 2) + 4 * hi;
                O0[r] += Oex[qh * 2048 + qloc * 64 + l31];
                O1[r] += Oex[qh * 2048 + qloc * 64 + 32 + l31];
                lf[r] = __shfl(linv, qloc, 32);
            }
#pragma unroll
            for (int r = 0; r < 16; ++r) {
                int qloc = (r & 3) + 8 * (r >> 2) + 4 * hi;
                int token = wq0 + qloc;
                size_t ob = ((size_t)(b * L_SEQ + token)) * DMODEL + h * DHEAD;
                Ao[ob + l31]      = f2b(O0[r] * lf[r]);
                Ao[ob + 32 + l31] = f2b(O1[r] * lf[r]);
            }
        }
    }
}

// ---------------------------------------------------------------------------
extern "C" void kernel_launch(void* const* d_in, const int* in_sizes, int n_in,
                              void* d_out, int out_size, void* d_ws, size_t ws_size,
                              hipStream_t stream) {
    const float* x      = (const float*)d_in[0];   // [B, L, D]
    const float* w_qkv  = (const float*)d_in[1];   // [D, 3D]
    const float* w_proj = (const float*)d_in[2];   // [D, D]
    // d_in[3] num_prefix_tokens: unused — reference mask reduces to pure causal.
    float* out = (float*)d_out;                    // [B, L, D] fp32

    unsigned short* ws     = (unsigned short*)d_ws;
    unsigned short* wqkvT  = ws;                         // 3,145,728  [3072][1024]
    unsigned short* wprojT = wqkvT + 3145728;            // 1,048,576  [1024][1024]
    unsigned short* qkv    = wprojT + 1048576;           // Q,K [bh][l][d]; V^T [bh][d][l]
    unsigned short* ao     = qkv + 3 * (size_t)SEG;      // 4,194,304

    prep<<<1024, 256, 0, stream>>>(w_qkv, w_proj, wqkvT, wprojT);

    gemm_qkv<<<dim3(24, 32), 256, 0, stream>>>(x, wqkvT, qkv);

    attn_mfma<<<512, 256, 0, stream>>>(qkv, qkv + SEG, qkv + 2 * (size_t)SEG, ao);

    gemm_proj<<<dim3(8, 32), 256, 0, stream>>>(ao, wprojT, out);
}

// Round 9
// 187.724 us; speedup vs baseline: 1.1946x; 1.1946x over previous
//
#include <hip/hip_runtime.h>
#include <hip/hip_bf16.h>

#define BATCH   2
#define L_SEQ   2048
#define DMODEL  1024
#define NHEADS  16
#define DHEAD   64
#define SEG     (BATCH*NHEADS*L_SEQ*DHEAD)   // 4,194,304 elements per q/k/v segment

typedef __attribute__((ext_vector_type(8)))  short bf16x8;
typedef __attribute__((ext_vector_type(4)))  float f32x4;
typedef __attribute__((ext_vector_type(16))) float f32x16;

__device__ __forceinline__ unsigned short f2b(float f) {
    unsigned int u = __float_as_uint(f);
    return (unsigned short)((u + 0x7FFFu + ((u >> 16) & 1u)) >> 16);   // RNE
}
__device__ __forceinline__ unsigned int pk2(float a, float b) {
    __hip_bfloat162 h = __float22bfloat162_rn(make_float2(a, b));
    return *(unsigned int*)&h;
}
__device__ __forceinline__ void glds16(const unsigned short* g, unsigned short* l) {
    __builtin_amdgcn_global_load_lds(
        (const __attribute__((address_space(1))) unsigned int*)g,
        (__attribute__((address_space(3))) unsigned int*)l, 16, 0, 0);
}

// ---------------------------------------------------------------------------
// prep: 5120 blocks. 0..4095 cast x->bf16; 4096..4863 transpose-cast w_qkv;
// 4864..5119 transpose-cast w_proj.
// ---------------------------------------------------------------------------
__device__ __forceinline__ void tcast64(const float* __restrict__ in,
                                        unsigned short* __restrict__ out,
                                        int K, int N, int bx, int by, int t) {
    __shared__ unsigned short T[64][65];
    const int k0 = by * 64, n0 = bx * 64;
    const int r = t >> 4, c4 = (t & 15) * 4;
#pragma unroll
    for (int rep = 0; rep < 4; ++rep) {
        int kk = rep * 16 + r;
        float4 f = *(const float4*)&in[(size_t)(k0 + kk) * N + n0 + c4];
        T[kk][c4 + 0] = f2b(f.x);
        T[kk][c4 + 1] = f2b(f.y);
        T[kk][c4 + 2] = f2b(f.z);
        T[kk][c4 + 3] = f2b(f.w);
    }
    __syncthreads();
#pragma unroll
    for (int rep = 0; rep < 4; ++rep) {
        int nn = rep * 16 + r;
        ushort4 o;
        o.x = T[c4 + 0][nn];
        o.y = T[c4 + 1][nn];
        o.z = T[c4 + 2][nn];
        o.w = T[c4 + 3][nn];
        *(ushort4*)&out[(size_t)(n0 + nn) * K + k0 + c4] = o;
    }
}

__global__ __launch_bounds__(256)
void prep(const float* __restrict__ x, const float* __restrict__ wqkv,
          const float* __restrict__ wproj, unsigned short* __restrict__ xb,
          unsigned short* __restrict__ wqkvT, unsigned short* __restrict__ wprojT) {
    const int id = blockIdx.x, t = threadIdx.x;
    if (id < 4096) {
        int i = id * 1024 + t * 4;
        float4 f = *(const float4*)&x[i];
        ushort4 o;
        o.x = f2b(f.x); o.y = f2b(f.y); o.z = f2b(f.z); o.w = f2b(f.w);
        *(ushort4*)&xb[i] = o;
    } else if (id < 4864) {
        int lid = id - 4096;
        tcast64(wqkv, wqkvT, DMODEL, 3 * DMODEL, lid % 48, lid / 48, t);
    } else {
        int lid = id - 4864;
        tcast64(wproj, wprojT, DMODEL, DMODEL, lid & 15, lid >> 4, t);
    }
}

// ---------------------------------------------------------------------------
// QKV GEMM: C = xb[4096,1024] @ wqkvT[3072,1024]^T. 128x128 tile, BK=64,
// glds16 staging (both A and B) + XOR source-chunk swizzle, 2-barrier K-loop.
// Epilogue: acc -> swizzled 32KB LDS tile -> coalesced 16B stores.
// n0<2048: Q/K [bh][l][d] (Q scaled 0.125*log2e). n0>=2048: operand-swapped
// MFMAs (acc = C^T: feature = wn+j*16+quad*4+r, token = wm+i*16+l16)
// -> V^T [bh][d][L].
// ---------------------------------------------------------------------------
__global__ __launch_bounds__(256)
void gemm_qkv(const unsigned short* __restrict__ A, const unsigned short* __restrict__ Bt,
              unsigned short* __restrict__ Cb) {
    __shared__ unsigned short SLDS[128 * 128];   // 32 KB: A(16K)+B(16K), then epilogue
    unsigned short* Asm = SLDS;
    unsigned short* Bsm = SLDS + 128 * 64;

    const int t = threadIdx.x;
    const int lane = t & 63, wave = t >> 6;
    const int quad = lane >> 4, l16 = lane & 15;
    const int wm = (wave >> 1) * 64, wn = (wave & 1) * 64;
    const int m0 = blockIdx.y * 128, n0 = blockIdx.x * 128;
    const bool vrole = (n0 >= 2048);

    const int gsw = (lane & 7) ^ (lane >> 3);
    const unsigned short* ga[4];
    const unsigned short* gb[4];
    unsigned short* la[4];
    unsigned short* lb[4];
#pragma unroll
    for (int i = 0; i < 4; ++i) {
        int row = wave * 32 + i * 8 + (lane >> 3);
        ga[i] = &A[(size_t)(m0 + row) * DMODEL + gsw * 8];
        gb[i] = &Bt[(size_t)(n0 + row) * DMODEL + gsw * 8];
        la[i] = &Asm[(wave * 32 + i * 8) * 64];
        lb[i] = &Bsm[(wave * 32 + i * 8) * 64];
    }
    const int sx = l16 & 7;

    f32x4 acc[4][4];
#pragma unroll
    for (int i = 0; i < 4; ++i)
#pragma unroll
        for (int j = 0; j < 4; ++j)
#pragma unroll
            for (int r = 0; r < 4; ++r) acc[i][j][r] = 0.0f;

    for (int k0 = 0; k0 < DMODEL; k0 += 64) {
        __syncthreads();   // prior frag reads done
#pragma unroll
        for (int i = 0; i < 4; ++i) {
            glds16(ga[i] + k0, la[i]);
            glds16(gb[i] + k0, lb[i]);
        }
        __syncthreads();   // drain vmcnt -> LDS valid
#pragma unroll
        for (int s = 0; s < 2; ++s) {
            bf16x8 af[4], bfr[4];
#pragma unroll
            for (int i = 0; i < 4; ++i)
                af[i] = *(const bf16x8*)&Asm[(wm + i * 16 + l16) * 64 + ((4 * s + quad) ^ sx) * 8];
#pragma unroll
            for (int j = 0; j < 4; ++j)
                bfr[j] = *(const bf16x8*)&Bsm[(wn + j * 16 + l16) * 64 + ((4 * s + quad) ^ sx) * 8];
            if (!vrole) {
#pragma unroll
                for (int i = 0; i < 4; ++i)
#pragma unroll
                    for (int j = 0; j < 4; ++j)
                        acc[i][j] = __builtin_amdgcn_mfma_f32_16x16x32_bf16(af[i], bfr[j], acc[i][j], 0, 0, 0);
            } else {   // C^T: rows=features, cols=tokens
#pragma unroll
                for (int i = 0; i < 4; ++i)
#pragma unroll
                    for (int j = 0; j < 4; ++j)
                        acc[i][j] = __builtin_amdgcn_mfma_f32_16x16x32_bf16(bfr[j], af[i], acc[i][j], 0, 0, 0);
            }
        }
    }

    // ---- epilogue: acc -> swizzled LDS tile [128][128] -> coalesced stores
    const float qscale = 0.1803368801111244f;   // 0.125 * log2(e)
    const float scl = (!vrole && n0 < 1024) ? qscale : 1.0f;
    __syncthreads();   // all frag reads done before overwriting SLDS
#pragma unroll
    for (int i = 0; i < 4; ++i)
#pragma unroll
        for (int r = 0; r < 4; ++r) {
#pragma unroll
            for (int j = 0; j < 4; ++j) {
                int row_l, col_l;
                if (!vrole) {            // [token][feature]
                    row_l = wm + i * 16 + quad * 4 + r;
                    col_l = wn + j * 16 + l16;
                } else {                 // [feature][token] (acc is C^T)
                    row_l = wn + j * 16 + quad * 4 + r;
                    col_l = wm + i * 16 + l16;
                }
                int key = row_l & 7;
                SLDS[row_l * 128 + (((col_l >> 3) ^ key) * 8) + (col_l & 7)] =
                    f2b(acc[i][j][r] * scl);
            }
        }
    __syncthreads();

    const int s0 = n0 >> 10;        // 0=Q, 1=K (vrole handled separately)
    const int bb = m0 >> 11;        // batch index (tile never crosses)
#pragma unroll
    for (int it = 0; it < 4; ++it) {
        int row = it * 32 + (t >> 3);
        int c = t & 7;
        int key = row & 7;
        bf16x8 v0 = *(const bf16x8*)&SLDS[row * 128 + ((c ^ key) * 8)];
        bf16x8 v1 = *(const bf16x8*)&SLDS[row * 128 + (((c + 8) ^ key) * 8)];
        if (!vrole) {
            int token = m0 + row, lp = token & (L_SEQ - 1);
            int n_a = n0 + c * 8,        h_a = (n_a >> 6) & 15, d_a = n_a & 63;
            int n_b = n0 + (c + 8) * 8,  h_b = (n_b >> 6) & 15, d_b = n_b & 63;
            size_t base = (size_t)s0 * SEG;
            *(bf16x8*)&Cb[base + (((size_t)(bb * NHEADS + h_a) * L_SEQ + lp) * DHEAD) + d_a] = v0;
            *(bf16x8*)&Cb[base + (((size_t)(bb * NHEADS + h_b) * L_SEQ + lp) * DHEAD) + d_b] = v1;
        } else {
            int fr = (n0 - 2048) + row;
            int h = fr >> 6, dd = fr & 63;
            int lp0 = (m0 & (L_SEQ - 1));
            size_t base = 2 * (size_t)SEG +
                          (((size_t)(bb * NHEADS + h) * DHEAD + dd) * L_SEQ) + lp0;
            *(bf16x8*)&Cb[base + c * 8]       = v0;
            *(bf16x8*)&Cb[base + (c + 8) * 8] = v1;
        }
    }
}

// ---------------------------------------------------------------------------
// proj GEMM: out = ao[4096,1024] @ wprojT[1024,1024]^T, fp32 store.
// 64x64 tile -> 1024 blocks (4/CU; the 128x128 version was 256 blocks =
// 1 block/CU = 4 waves/CU, dispatch-limited). 4 waves in 2x2, each 32x32.
// ---------------------------------------------------------------------------
__global__ __launch_bounds__(256)
void gemm_proj(const unsigned short* __restrict__ A, const unsigned short* __restrict__ Bt,
               float* __restrict__ Cf) {
    __shared__ unsigned short Asm[64 * 64];
    __shared__ unsigned short Bsm[64 * 64];

    const int t = threadIdx.x;
    const int lane = t & 63, wave = t >> 6;
    const int quad = lane >> 4, l16 = lane & 15;
    const int wm = (wave >> 1) * 32, wn = (wave & 1) * 32;
    const int m0 = blockIdx.y * 64, n0 = blockIdx.x * 64;
    const int K = DMODEL, N = DMODEL;

    const int gsw = (lane & 7) ^ (lane >> 3);
    const unsigned short* ga[2];
    const unsigned short* gb[2];
    unsigned short* la[2];
    unsigned short* lb[2];
#pragma unroll
    for (int i = 0; i < 2; ++i) {
        int row = wave * 8 + i * 32 + (lane >> 3);
        ga[i] = &A[(size_t)(m0 + row) * K + gsw * 8];
        gb[i] = &Bt[(size_t)(n0 + row) * K + gsw * 8];
        la[i] = &Asm[(wave * 8 + i * 32) * 64];
        lb[i] = &Bsm[(wave * 8 + i * 32) * 64];
    }
    const int sx = l16 & 7;

    f32x4 acc[2][2];
#pragma unroll
    for (int i = 0; i < 2; ++i)
#pragma unroll
        for (int j = 0; j < 2; ++j)
#pragma unroll
            for (int r = 0; r < 4; ++r) acc[i][j][r] = 0.0f;

    for (int k0 = 0; k0 < K; k0 += 64) {
        __syncthreads();
#pragma unroll
        for (int i = 0; i < 2; ++i) {
            glds16(ga[i] + k0, la[i]);
            glds16(gb[i] + k0, lb[i]);
        }
        __syncthreads();
#pragma unroll
        for (int s = 0; s < 2; ++s) {
            bf16x8 af[2], bfr[2];
#pragma unroll
            for (int i = 0; i < 2; ++i)
                af[i] = *(const bf16x8*)&Asm[(wm + i * 16 + l16) * 64 + ((4 * s + quad) ^ sx) * 8];
#pragma unroll
            for (int j = 0; j < 2; ++j)
                bfr[j] = *(const bf16x8*)&Bsm[(wn + j * 16 + l16) * 64 + ((4 * s + quad) ^ sx) * 8];
#pragma unroll
            for (int i = 0; i < 2; ++i)
#pragma unroll
                for (int j = 0; j < 2; ++j)
                    acc[i][j] = __builtin_amdgcn_mfma_f32_16x16x32_bf16(af[i], bfr[j], acc[i][j], 0, 0, 0);
        }
    }

#pragma unroll
    for (int i = 0; i < 2; ++i)
#pragma unroll
        for (int r = 0; r < 4; ++r) {
            int row = m0 + wm + i * 16 + quad * 4 + r;
#pragma unroll
            for (int j = 0; j < 2; ++j)
                Cf[(size_t)row * N + n0 + wn + j * 16 + l16] = acc[i][j][r];
        }
}

// ---------------------------------------------------------------------------
// Flash causal attention, 32x32x16 MFMA, S^T form, FIXED-max softmax (m=0).
// 512 UNIFORM blocks: block (p,bh) runs q-tiles 31-p then p = 17 strips
// exactly -> no tail. 4 waves: qhalf = w&1 (32 q), kpar = w>>1 (64-key half
// of each 128-key strip). Chunked XOR LDS, register prefetch (incl. across
// the half boundary). kp=1 waves merge O/rs into kp=0 via LDS per half.
// ---------------------------------------------------------------------------
__global__ __launch_bounds__(256)
void attn_mfma(const unsigned short* __restrict__ Qg, const unsigned short* __restrict__ Kg,
               const unsigned short* __restrict__ Vg, unsigned short* __restrict__ Ao) {
    __shared__ unsigned short Ksm[128 * 64];
    __shared__ unsigned short Vsm[64 * 128];
    __shared__ unsigned short Psm[4 * 32 * 64];

    const int t = threadIdx.x;
    const int lane = t & 63, wave = t >> 6;
    const int l31 = lane & 31, hi = lane >> 5;
    const int bh = blockIdx.x & 31, p = blockIdx.x >> 5;   // p = 0..15
    const int qh = wave & 1, kp = wave >> 1;
    const int b = bh >> 4, h = bh & 15;
    const size_t qkbase = (size_t)bh * L_SEQ * DHEAD;
    const size_t vbase  = (size_t)bh * DHEAD * L_SEQ;

    const int kc0 = t & 7,  kr0 = (t >> 3) * 4;
    const int vc0 = t & 15, vd0 = (t >> 4) * 4;
    unsigned short* Pw = Psm + wave * 32 * 64;

    bf16x8 gk[4], gv[4];
#pragma unroll
    for (int i = 0; i < 4; ++i) {
        gk[i] = *(const bf16x8*)&Kg[qkbase + (size_t)(kr0 + i) * DHEAD + kc0 * 8];
        gv[i] = *(const bf16x8*)&Vg[vbase + (size_t)(vd0 + i) * L_SEQ + vc0 * 8];
    }

#pragma unroll
    for (int half = 0; half < 2; ++half) {
        const int Qt = (half == 0) ? (31 - p) : p;
        const int wq0 = Qt * 64 + qh * 32;
        const int nstrip = (Qt >> 1) + 1;

        bf16x8 bq[4];
#pragma unroll
        for (int ks = 0; ks < 4; ++ks)
            bq[ks] = *(const bf16x8*)&Qg[qkbase + (size_t)(wq0 + l31) * DHEAD + ks * 16 + hi * 8];

        f32x16 O0, O1;
#pragma unroll
        for (int r = 0; r < 16; ++r) { O0[r] = 0.0f; O1[r] = 0.0f; }
        float rs = 0.0f;

        for (int s = 0; s < nstrip; ++s) {
            __syncthreads();
#pragma unroll
            for (int i = 0; i < 4; ++i) {
                *(bf16x8*)&Ksm[(kc0 * 128 + ((kr0 + i) ^ kc0)) * 8] = gk[i];
                *(bf16x8*)&Vsm[(vc0 * 64 + ((vd0 + i) ^ vc0)) * 8] = gv[i];
            }
            if (s + 1 < nstrip || half == 0) {
                const int kn = (s + 1 < nstrip) ? (s + 1) * 128 : 0;
#pragma unroll
                for (int i = 0; i < 4; ++i) {
                    gk[i] = *(const bf16x8*)&Kg[qkbase + (size_t)(kn + kr0 + i) * DHEAD + kc0 * 8];
                    gv[i] = *(const bf16x8*)&Vg[vbase + (size_t)(vd0 + i) * L_SEQ + kn + vc0 * 8];
                }
            }
            __syncthreads();

            const int keybase = s * 128 + kp * 64;
            if (keybase <= wq0 + 31) {
                f32x16 ST[2];
#pragma unroll
                for (int kh = 0; kh < 2; ++kh) {
#pragma unroll
                    for (int r = 0; r < 16; ++r) ST[kh][r] = 0.0f;
#pragma unroll
                    for (int ks = 0; ks < 4; ++ks) {
                        const int c = ks * 2 + hi;
                        const int rk = kp * 64 + kh * 32 + l31;
                        bf16x8 a = *(const bf16x8*)&Ksm[(c * 128 + (rk ^ c)) * 8];
                        ST[kh] = __builtin_amdgcn_mfma_f32_32x32x16_bf16(a, bq[ks], ST[kh], 0, 0, 0);
                    }
                }

                if (keybase + 63 > wq0) {   // diagonal: causal mask
                    const int qg = wq0 + l31;
#pragma unroll
                    for (int kh = 0; kh < 2; ++kh)
#pragma unroll
                        for (int r = 0; r < 16; ++r) {
                            int keyg = keybase + kh * 32 + (r & 3) + 8 * (r >> 2) + 4 * hi;
                            if (keyg > qg) ST[kh][r] = -1e30f;
                        }
                }

#pragma unroll
                for (int kh = 0; kh < 2; ++kh)
#pragma unroll
                    for (int g = 0; g < 4; ++g) {
                        float p0 = __builtin_amdgcn_exp2f(ST[kh][4 * g + 0]);
                        float p1 = __builtin_amdgcn_exp2f(ST[kh][4 * g + 1]);
                        float p2 = __builtin_amdgcn_exp2f(ST[kh][4 * g + 2]);
                        float p3 = __builtin_amdgcn_exp2f(ST[kh][4 * g + 3]);
                        rs += (p0 + p1) + (p2 + p3);
                        const int c = kh * 4 + g;
                        *(uint2*)&Pw[(c * 32 + (l31 ^ c)) * 8 + hi * 4] =
                            make_uint2(pk2(p0, p1), pk2(p2, p3));
                    }

#pragma unroll
                for (int ks = 0; ks < 4; ++ks) {
                    const int cp = ks * 2 + hi;
                    const int cv = kp * 8 + ks * 2 + hi;
                    bf16x8 pa = *(const bf16x8*)&Pw[(cp * 32 + (l31 ^ cp)) * 8];
                    bf16x8 v0 = *(const bf16x8*)&Vsm[(cv * 64 + (l31 ^ cv)) * 8];
                    bf16x8 v1 = *(const bf16x8*)&Vsm[(cv * 64 + ((32 + l31) ^ cv)) * 8];
                    O0 = __builtin_amdgcn_mfma_f32_32x32x16_bf16(pa, v0, O0, 0, 0, 0);
                    O1 = __builtin_amdgcn_mfma_f32_32x32x16_bf16(pa, v1, O1, 0, 0, 0);
                }
            }
        }

        rs += __shfl_xor(rs, 32, 64);

        // merge key-parities via LDS (Ksm/Vsm reused as scratch)
        __syncthreads();
        float* Oex = (float*)Ksm;
        float* Rex = (float*)Vsm;
        if (kp == 1) {
#pragma unroll
            for (int r = 0; r < 16; ++r) {
                int qloc = (r & 3) + 8 * (r >> 2) + 4 * hi;
                Oex[qh * 2048 + qloc * 64 + l31]      = O0[r];
                Oex[qh * 2048 + qloc * 64 + 32 + l31] = O1[r];
            }
            if (hi == 0) Rex[qh * 32 + l31] = rs;
        }
        __syncthreads();
        if (kp == 0) {
            float rs_tot = rs + Rex[qh * 32 + l31];
            float linv = 1.0f / rs_tot;
            float lf[16];
#pragma unroll
            for (int r = 0; r < 16; ++r) {
                int qloc = (r & 3) + 8 * (r >> 2) + 4 * hi;
                O0[r] += Oex[qh * 2048 + qloc * 64 + l31];
                O1[r] += Oex[qh * 2048 + qloc * 64 + 32 + l31];
                lf[r] = __shfl(linv, qloc, 32);
            }
#pragma unroll
            for (int r = 0; r < 16; ++r) {
                int qloc = (r & 3) + 8 * (r >> 2) + 4 * hi;
                int token = wq0 + qloc;
                size_t ob = ((size_t)(b * L_SEQ + token)) * DMODEL + h * DHEAD;
                Ao[ob + l31]      = f2b(O0[r] * lf[r]);
                Ao[ob + 32 + l31] = f2b(O1[r] * lf[r]);
            }
        }
    }
}

// ---------------------------------------------------------------------------
extern "C" void kernel_launch(void* const* d_in, const int* in_sizes, int n_in,
                              void* d_out, int out_size, void* d_ws, size_t ws_size,
                              hipStream_t stream) {
    const float* x      = (const float*)d_in[0];   // [B, L, D]
    const float* w_qkv  = (const float*)d_in[1];   // [D, 3D]
    const float* w_proj = (const float*)d_in[2];   // [D, D]
    // d_in[3] num_prefix_tokens: unused — reference mask reduces to pure causal.
    float* out = (float*)d_out;                    // [B, L, D] fp32

    unsigned short* ws     = (unsigned short*)d_ws;
    unsigned short* xb     = ws;                         // 4,194,304
    unsigned short* wqkvT  = xb + 4194304;               // 3,145,728  [3072][1024]
    unsigned short* wprojT = wqkvT + 3145728;            // 1,048,576  [1024][1024]
    unsigned short* qkv    = wprojT + 1048576;           // Q,K [bh][l][d]; V^T [bh][d][l]
    unsigned short* ao     = qkv + 3 * (size_t)SEG;      // 4,194,304

    prep<<<5120, 256, 0, stream>>>(x, w_qkv, w_proj, xb, wqkvT, wprojT);

    gemm_qkv<<<dim3(24, 32), 256, 0, stream>>>(xb, wqkvT, qkv);

    attn_mfma<<<512, 256, 0, stream>>>(qkv, qkv + SEG, qkv + 2 * (size_t)SEG, ao);

    gemm_proj<<<dim3(16, 64), 256, 0, stream>>>(ao, wprojT, out);
}

// Round 10
// 176.693 us; speedup vs baseline: 1.2692x; 1.0624x over previous
//
#include <hip/hip_runtime.h>
#include <hip/hip_bf16.h>

#define BATCH   2
#define L_SEQ   2048
#define DMODEL  1024
#define NHEADS  16
#define DHEAD   64
#define SEG     (BATCH*NHEADS*L_SEQ*DHEAD)   // 4,194,304 elements per q/k/v segment

typedef __attribute__((ext_vector_type(8)))  short bf16x8;
typedef __attribute__((ext_vector_type(4)))  float f32x4;
typedef __attribute__((ext_vector_type(16))) float f32x16;

__device__ __forceinline__ unsigned short f2b(float f) {
    unsigned int u = __float_as_uint(f);
    return (unsigned short)((u + 0x7FFFu + ((u >> 16) & 1u)) >> 16);   // RNE
}
__device__ __forceinline__ unsigned int pk2(float a, float b) {
    __hip_bfloat162 h = __float22bfloat162_rn(make_float2(a, b));
    return *(unsigned int*)&h;
}
__device__ __forceinline__ void glds16(const unsigned short* g, unsigned short* l) {
    __builtin_amdgcn_global_load_lds(
        (const __attribute__((address_space(1))) unsigned int*)g,
        (__attribute__((address_space(3))) unsigned int*)l, 16, 0, 0);
}

// ---------------------------------------------------------------------------
// prep: 5120 blocks. 0..4095 cast x->bf16; 4096..4863 transpose-cast w_qkv;
// 4864..5119 transpose-cast w_proj.
// ---------------------------------------------------------------------------
__device__ __forceinline__ void tcast64(const float* __restrict__ in,
                                        unsigned short* __restrict__ out,
                                        int K, int N, int bx, int by, int t) {
    __shared__ unsigned short T[64][65];
    const int k0 = by * 64, n0 = bx * 64;
    const int r = t >> 4, c4 = (t & 15) * 4;
#pragma unroll
    for (int rep = 0; rep < 4; ++rep) {
        int kk = rep * 16 + r;
        float4 f = *(const float4*)&in[(size_t)(k0 + kk) * N + n0 + c4];
        T[kk][c4 + 0] = f2b(f.x);
        T[kk][c4 + 1] = f2b(f.y);
        T[kk][c4 + 2] = f2b(f.z);
        T[kk][c4 + 3] = f2b(f.w);
    }
    __syncthreads();
#pragma unroll
    for (int rep = 0; rep < 4; ++rep) {
        int nn = rep * 16 + r;
        ushort4 o;
        o.x = T[c4 + 0][nn];
        o.y = T[c4 + 1][nn];
        o.z = T[c4 + 2][nn];
        o.w = T[c4 + 3][nn];
        *(ushort4*)&out[(size_t)(n0 + nn) * K + k0 + c4] = o;
    }
}

__global__ __launch_bounds__(256)
void prep(const float* __restrict__ x, const float* __restrict__ wqkv,
          const float* __restrict__ wproj, unsigned short* __restrict__ xb,
          unsigned short* __restrict__ wqkvT, unsigned short* __restrict__ wprojT) {
    const int id = blockIdx.x, t = threadIdx.x;
    if (id < 4096) {
        int i = id * 1024 + t * 4;
        float4 f = *(const float4*)&x[i];
        ushort4 o;
        o.x = f2b(f.x); o.y = f2b(f.y); o.z = f2b(f.z); o.w = f2b(f.w);
        *(ushort4*)&xb[i] = o;
    } else if (id < 4864) {
        int lid = id - 4096;
        tcast64(wqkv, wqkvT, DMODEL, 3 * DMODEL, lid % 48, lid / 48, t);
    } else {
        int lid = id - 4864;
        tcast64(wproj, wprojT, DMODEL, DMODEL, lid & 15, lid >> 4, t);
    }
}

// ---------------------------------------------------------------------------
// QKV GEMM: C = xb[4096,1024] @ wqkvT[3072,1024]^T. 128x128 tile, BK=64,
// glds16 staging + XOR source-chunk swizzle, 2-barrier K-loop.
// XCD-OWNERSHIP REMAP: id&7 -> XCD (round-robin dispatch heuristic); each
// XCD owns 4 contiguous m-rows, walked x-major -> A panel fetched once per
// XCD (1 MB working set) instead of every XCD walking all 32 rows (8x A
// re-fetch = r8's 73.8 MB FETCH_SIZE).
// Epilogue: acc -> swizzled 32KB LDS tile -> coalesced 16B stores.
// n0<2048: Q/K [bh][l][d] (Q scaled 0.125*log2e). n0>=2048: operand-swapped
// MFMAs (acc = C^T) -> V^T [bh][d][L].
// ---------------------------------------------------------------------------
__global__ __launch_bounds__(256)
void gemm_qkv(const unsigned short* __restrict__ A, const unsigned short* __restrict__ Bt,
              unsigned short* __restrict__ Cb) {
    __shared__ unsigned short SLDS[128 * 128];   // 32 KB: A(16K)+B(16K), then epilogue
    unsigned short* Asm = SLDS;
    unsigned short* Bsm = SLDS + 128 * 64;

    const int t = threadIdx.x;
    const int lane = t & 63, wave = t >> 6;
    const int quad = lane >> 4, l16 = lane & 15;
    const int wm = (wave >> 1) * 64, wn = (wave & 1) * 64;
    // XCD remap: grid must be 24x32 (768 blocks)
    const int id = blockIdx.y * gridDim.x + blockIdx.x;
    const int xcd = id & 7, sq = id >> 3;          // sq in [0,96)
    const int m0 = (xcd * 4 + sq / 24) * 128;      // 4 m-rows per XCD
    const int n0 = (sq % 24) * 128;                // x-major within XCD
    const bool vrole = (n0 >= 2048);

    const int gsw = (lane & 7) ^ (lane >> 3);
    const unsigned short* ga[4];
    const unsigned short* gb[4];
    unsigned short* la[4];
    unsigned short* lb[4];
#pragma unroll
    for (int i = 0; i < 4; ++i) {
        int row = wave * 32 + i * 8 + (lane >> 3);
        ga[i] = &A[(size_t)(m0 + row) * DMODEL + gsw * 8];
        gb[i] = &Bt[(size_t)(n0 + row) * DMODEL + gsw * 8];
        la[i] = &Asm[(wave * 32 + i * 8) * 64];
        lb[i] = &Bsm[(wave * 32 + i * 8) * 64];
    }
    const int sx = l16 & 7;

    f32x4 acc[4][4];
#pragma unroll
    for (int i = 0; i < 4; ++i)
#pragma unroll
        for (int j = 0; j < 4; ++j)
#pragma unroll
            for (int r = 0; r < 4; ++r) acc[i][j][r] = 0.0f;

    for (int k0 = 0; k0 < DMODEL; k0 += 64) {
        __syncthreads();   // prior frag reads done
#pragma unroll
        for (int i = 0; i < 4; ++i) {
            glds16(ga[i] + k0, la[i]);
            glds16(gb[i] + k0, lb[i]);
        }
        __syncthreads();   // drain vmcnt -> LDS valid
#pragma unroll
        for (int s = 0; s < 2; ++s) {
            bf16x8 af[4], bfr[4];
#pragma unroll
            for (int i = 0; i < 4; ++i)
                af[i] = *(const bf16x8*)&Asm[(wm + i * 16 + l16) * 64 + ((4 * s + quad) ^ sx) * 8];
#pragma unroll
            for (int j = 0; j < 4; ++j)
                bfr[j] = *(const bf16x8*)&Bsm[(wn + j * 16 + l16) * 64 + ((4 * s + quad) ^ sx) * 8];
            if (!vrole) {
#pragma unroll
                for (int i = 0; i < 4; ++i)
#pragma unroll
                    for (int j = 0; j < 4; ++j)
                        acc[i][j] = __builtin_amdgcn_mfma_f32_16x16x32_bf16(af[i], bfr[j], acc[i][j], 0, 0, 0);
            } else {   // C^T: rows=features, cols=tokens
#pragma unroll
                for (int i = 0; i < 4; ++i)
#pragma unroll
                    for (int j = 0; j < 4; ++j)
                        acc[i][j] = __builtin_amdgcn_mfma_f32_16x16x32_bf16(bfr[j], af[i], acc[i][j], 0, 0, 0);
            }
        }
    }

    // ---- epilogue: acc -> swizzled LDS tile [128][128] -> coalesced stores
    const float qscale = 0.1803368801111244f;   // 0.125 * log2(e)
    const float scl = (!vrole && n0 < 1024) ? qscale : 1.0f;
    __syncthreads();   // all frag reads done before overwriting SLDS
#pragma unroll
    for (int i = 0; i < 4; ++i)
#pragma unroll
        for (int r = 0; r < 4; ++r) {
#pragma unroll
            for (int j = 0; j < 4; ++j) {
                int row_l, col_l;
                if (!vrole) {            // [token][feature]
                    row_l = wm + i * 16 + quad * 4 + r;
                    col_l = wn + j * 16 + l16;
                } else {                 // [feature][token] (acc is C^T)
                    row_l = wn + j * 16 + quad * 4 + r;
                    col_l = wm + i * 16 + l16;
                }
                int key = row_l & 7;
                SLDS[row_l * 128 + (((col_l >> 3) ^ key) * 8) + (col_l & 7)] =
                    f2b(acc[i][j][r] * scl);
            }
        }
    __syncthreads();

    const int s0 = n0 >> 10;        // 0=Q, 1=K (vrole handled separately)
    const int bb = m0 >> 11;        // batch index (tile never crosses)
#pragma unroll
    for (int it = 0; it < 4; ++it) {
        int row = it * 32 + (t >> 3);
        int c = t & 7;
        int key = row & 7;
        bf16x8 v0 = *(const bf16x8*)&SLDS[row * 128 + ((c ^ key) * 8)];
        bf16x8 v1 = *(const bf16x8*)&SLDS[row * 128 + (((c + 8) ^ key) * 8)];
        if (!vrole) {
            int token = m0 + row, lp = token & (L_SEQ - 1);
            int n_a = n0 + c * 8,        h_a = (n_a >> 6) & 15, d_a = n_a & 63;
            int n_b = n0 + (c + 8) * 8,  h_b = (n_b >> 6) & 15, d_b = n_b & 63;
            size_t base = (size_t)s0 * SEG;
            *(bf16x8*)&Cb[base + (((size_t)(bb * NHEADS + h_a) * L_SEQ + lp) * DHEAD) + d_a] = v0;
            *(bf16x8*)&Cb[base + (((size_t)(bb * NHEADS + h_b) * L_SEQ + lp) * DHEAD) + d_b] = v1;
        } else {
            int fr = (n0 - 2048) + row;
            int h = fr >> 6, dd = fr & 63;
            int lp0 = (m0 & (L_SEQ - 1));
            size_t base = 2 * (size_t)SEG +
                          (((size_t)(bb * NHEADS + h) * DHEAD + dd) * L_SEQ) + lp0;
            *(bf16x8*)&Cb[base + c * 8]       = v0;
            *(bf16x8*)&Cb[base + (c + 8) * 8] = v1;
        }
    }
}

// ---------------------------------------------------------------------------
// proj GEMM: out = ao[4096,1024] @ wprojT[1024,1024]^T, fp32 store.
// 64x64 tile, 1024 blocks. XCD remap: each XCD owns 8 m-rows (A panel
// 1 MB/XCD fetched once), x-major walk.
// ---------------------------------------------------------------------------
__global__ __launch_bounds__(256)
void gemm_proj(const unsigned short* __restrict__ A, const unsigned short* __restrict__ Bt,
               float* __restrict__ Cf) {
    __shared__ unsigned short Asm[64 * 64];
    __shared__ unsigned short Bsm[64 * 64];

    const int t = threadIdx.x;
    const int lane = t & 63, wave = t >> 6;
    const int quad = lane >> 4, l16 = lane & 15;
    const int wm = (wave >> 1) * 32, wn = (wave & 1) * 32;
    // XCD remap: grid must be 16x64 (1024 blocks)
    const int id = blockIdx.y * gridDim.x + blockIdx.x;
    const int xcd = id & 7, sq = id >> 3;          // sq in [0,128)
    const int m0 = (xcd * 8 + (sq >> 4)) * 64;     // 8 m-rows per XCD
    const int n0 = (sq & 15) * 64;
    const int K = DMODEL, N = DMODEL;

    const int gsw = (lane & 7) ^ (lane >> 3);
    const unsigned short* ga[2];
    const unsigned short* gb[2];
    unsigned short* la[2];
    unsigned short* lb[2];
#pragma unroll
    for (int i = 0; i < 2; ++i) {
        int row = wave * 8 + i * 32 + (lane >> 3);
        ga[i] = &A[(size_t)(m0 + row) * K + gsw * 8];
        gb[i] = &Bt[(size_t)(n0 + row) * K + gsw * 8];
        la[i] = &Asm[(wave * 8 + i * 32) * 64];
        lb[i] = &Bsm[(wave * 8 + i * 32) * 64];
    }
    const int sx = l16 & 7;

    f32x4 acc[2][2];
#pragma unroll
    for (int i = 0; i < 2; ++i)
#pragma unroll
        for (int j = 0; j < 2; ++j)
#pragma unroll
            for (int r = 0; r < 4; ++r) acc[i][j][r] = 0.0f;

    for (int k0 = 0; k0 < K; k0 += 64) {
        __syncthreads();
#pragma unroll
        for (int i = 0; i < 2; ++i) {
            glds16(ga[i] + k0, la[i]);
            glds16(gb[i] + k0, lb[i]);
        }
        __syncthreads();
#pragma unroll
        for (int s = 0; s < 2; ++s) {
            bf16x8 af[2], bfr[2];
#pragma unroll
            for (int i = 0; i < 2; ++i)
                af[i] = *(const bf16x8*)&Asm[(wm + i * 16 + l16) * 64 + ((4 * s + quad) ^ sx) * 8];
#pragma unroll
            for (int j = 0; j < 2; ++j)
                bfr[j] = *(const bf16x8*)&Bsm[(wn + j * 16 + l16) * 64 + ((4 * s + quad) ^ sx) * 8];
#pragma unroll
            for (int i = 0; i < 2; ++i)
#pragma unroll
                for (int j = 0; j < 2; ++j)
                    acc[i][j] = __builtin_amdgcn_mfma_f32_16x16x32_bf16(af[i], bfr[j], acc[i][j], 0, 0, 0);
        }
    }

#pragma unroll
    for (int i = 0; i < 2; ++i)
#pragma unroll
        for (int r = 0; r < 4; ++r) {
            int row = m0 + wm + i * 16 + quad * 4 + r;
#pragma unroll
            for (int j = 0; j < 2; ++j)
                Cf[(size_t)row * N + n0 + wn + j * 16 + l16] = acc[i][j][r];
        }
}

// ---------------------------------------------------------------------------
// Flash causal attention (r6 structure, measured 44 us): 32x32x16 MFMA,
// S^T form, FIXED-max softmax (m=0, Q pre-scaled to log2 units -> pure
// linear accumulation; key dim splits freely).
// 1024 blocks = 32 bh x 32 q-tiles(64q); LPT (heavy first). 4 waves:
// qhalf = w&1 (32 q rows), kpar = w>>1 (64-key half of each 128-key strip).
// Chunked XOR LDS layout -> conflict-free b128 read AND write.
// kp=1 waves merge O/rs into kp=0 via LDS at the end.
// ---------------------------------------------------------------------------
__global__ __launch_bounds__(256)
void attn_mfma(const unsigned short* __restrict__ Qg, const unsigned short* __restrict__ Kg,
               const unsigned short* __restrict__ Vg, unsigned short* __restrict__ Ao) {
    __shared__ unsigned short Ksm[128 * 64];       // keys: 128 rows x 8 chunks
    __shared__ unsigned short Vsm[64 * 128];       // d: 64 rows x 16 key-chunks
    __shared__ unsigned short Psm[4 * 32 * 64];    // per-wave 32q x 8 chunks

    const int t = threadIdx.x;
    const int lane = t & 63, wave = t >> 6;
    const int l31 = lane & 31, hi = lane >> 5;
    const int bh = blockIdx.x & 31;
    const int Qt = 31 - (blockIdx.x >> 5);         // heavy tiles first
    const int q0 = Qt * 64;
    const int qh = wave & 1, kp = wave >> 1;
    const int wq0 = q0 + qh * 32;
    const int nstrip = (Qt >> 1) + 1;              // 128-key strips
    const int b = bh >> 4, h = bh & 15;
    const size_t qkbase = (size_t)bh * L_SEQ * DHEAD;
    const size_t vbase  = (size_t)bh * DHEAD * L_SEQ;

    // Q B-frags: n=q=l31(+wq0), k = ks*16 + hi*8 + j
    bf16x8 bq[4];
#pragma unroll
    for (int ks = 0; ks < 4; ++ks)
        bq[ks] = *(const bf16x8*)&Qg[qkbase + (size_t)(wq0 + l31) * DHEAD + ks * 16 + hi * 8];

    // staging assignments
    const int kc0 = t & 7,  kr0 = (t >> 3) * 4;    // K: rows kr0..+3, chunk kc0
    const int vc0 = t & 15, vd0 = (t >> 4) * 4;    // V: d vd0..+3, chunk vc0

    unsigned short* Pw = Psm + wave * 32 * 64;

    f32x16 O0, O1;
#pragma unroll
    for (int r = 0; r < 16; ++r) { O0[r] = 0.0f; O1[r] = 0.0f; }
    float rs = 0.0f;

    bf16x8 gk[4], gv[4];
#pragma unroll
    for (int i = 0; i < 4; ++i) {
        gk[i] = *(const bf16x8*)&Kg[qkbase + (size_t)(kr0 + i) * DHEAD + kc0 * 8];
        gv[i] = *(const bf16x8*)&Vg[vbase + (size_t)(vd0 + i) * L_SEQ + vc0 * 8];
    }

    for (int s = 0; s < nstrip; ++s) {
        __syncthreads();   // prior strip's LDS reads complete
#pragma unroll
        for (int i = 0; i < 4; ++i) {
            *(bf16x8*)&Ksm[(kc0 * 128 + ((kr0 + i) ^ kc0)) * 8] = gk[i];
            *(bf16x8*)&Vsm[(vc0 * 64 + ((vd0 + i) ^ vc0)) * 8] = gv[i];
        }
        if (s + 1 < nstrip) {
            const int kn = (s + 1) * 128;
#pragma unroll
            for (int i = 0; i < 4; ++i) {
                gk[i] = *(const bf16x8*)&Kg[qkbase + (size_t)(kn + kr0 + i) * DHEAD + kc0 * 8];
                gv[i] = *(const bf16x8*)&Vg[vbase + (size_t)(vd0 + i) * L_SEQ + kn + vc0 * 8];
            }
        }
        __syncthreads();

        const int keybase = s * 128 + kp * 64;     // wave's 64-key window
        if (keybase <= wq0 + 31) {
            // S^T = K·Q^T (rows=keys, cols=q)
            f32x16 ST[2];
#pragma unroll
            for (int kh = 0; kh < 2; ++kh) {
#pragma unroll
                for (int r = 0; r < 16; ++r) ST[kh][r] = 0.0f;
#pragma unroll
                for (int ks = 0; ks < 4; ++ks) {
                    const int c = ks * 2 + hi;
                    const int rk = kp * 64 + kh * 32 + l31;
                    bf16x8 a = *(const bf16x8*)&Ksm[(c * 128 + (rk ^ c)) * 8];
                    ST[kh] = __builtin_amdgcn_mfma_f32_32x32x16_bf16(a, bq[ks], ST[kh], 0, 0, 0);
                }
            }

            if (keybase + 63 > wq0) {   // diagonal: causal mask
                const int qg = wq0 + l31;
#pragma unroll
                for (int kh = 0; kh < 2; ++kh)
#pragma unroll
                    for (int r = 0; r < 16; ++r) {
                        int keyg = keybase + kh * 32 + (r & 3) + 8 * (r >> 2) + 4 * hi;
                        if (keyg > qg) ST[kh][r] = -1e30f;
                    }
            }

            // fixed-max softmax + pack P (wave-local strip)
#pragma unroll
            for (int kh = 0; kh < 2; ++kh)
#pragma unroll
                for (int g = 0; g < 4; ++g) {
                    float p0 = __builtin_amdgcn_exp2f(ST[kh][4 * g + 0]);
                    float p1 = __builtin_amdgcn_exp2f(ST[kh][4 * g + 1]);
                    float p2 = __builtin_amdgcn_exp2f(ST[kh][4 * g + 2]);
                    float p3 = __builtin_amdgcn_exp2f(ST[kh][4 * g + 3]);
                    rs += (p0 + p1) + (p2 + p3);
                    const int c = kh * 4 + g;
                    *(uint2*)&Pw[(c * 32 + (l31 ^ c)) * 8 + hi * 4] =
                        make_uint2(pk2(p0, p1), pk2(p2, p3));
                }

            // O += P·V
#pragma unroll
            for (int ks = 0; ks < 4; ++ks) {
                const int cp = ks * 2 + hi;
                const int cv = kp * 8 + ks * 2 + hi;
                bf16x8 pa = *(const bf16x8*)&Pw[(cp * 32 + (l31 ^ cp)) * 8];
                bf16x8 v0 = *(const bf16x8*)&Vsm[(cv * 64 + (l31 ^ cv)) * 8];
                bf16x8 v1 = *(const bf16x8*)&Vsm[(cv * 64 + ((32 + l31) ^ cv)) * 8];
                O0 = __builtin_amdgcn_mfma_f32_32x32x16_bf16(pa, v0, O0, 0, 0, 0);
                O1 = __builtin_amdgcn_mfma_f32_32x32x16_bf16(pa, v1, O1, 0, 0, 0);
            }
        }
    }

    rs += __shfl_xor(rs, 32, 64);   // lane now holds full-own-keys sum for q=l31

    // merge key-parities: kp=1 -> LDS -> kp=0 adds, normalizes, stores
    __syncthreads();
    float* Oex = (float*)Ksm;            // 2 * 32q * 64d * 4B = 16 KB
    float* Rex = (float*)Vsm;            // 2 * 32 floats
    if (kp == 1) {
#pragma unroll
        for (int r = 0; r < 16; ++r) {
            int qloc = (r & 3) + 8 * (r >> 2) + 4 * hi;
            Oex[qh * 2048 + qloc * 64 + l31]      = O0[r];
            Oex[qh * 2048 + qloc * 64 + 32 + l31] = O1[r];
        }
        if (hi == 0) Rex[qh * 32 + l31] = rs;
    }
    __syncthreads();
    if (kp == 0) {
        float rs_tot = rs + Rex[qh * 32 + l31];
        float linv = 1.0f / rs_tot;
        float lf[16];
#pragma unroll
        for (int r = 0; r < 16; ++r) {
            int qloc = (r & 3) + 8 * (r >> 2) + 4 * hi;
            O0[r] += Oex[qh * 2048 + qloc * 64 + l31];
            O1[r] += Oex[qh * 2048 + qloc * 64 + 32 + l31];
            lf[r] = __shfl(linv, qloc, 32);
        }
#pragma unroll
        for (int r = 0; r < 16; ++r) {
            int qloc = (r & 3) + 8 * (r >> 2) + 4 * hi;
            int token = wq0 + qloc;
            size_t ob = ((size_t)(b * L_SEQ + token)) * DMODEL + h * DHEAD;
            Ao[ob + l31]      = f2b(O0[r] * lf[r]);
            Ao[ob + 32 + l31] = f2b(O1[r] * lf[r]);
        }
    }
}

// ---------------------------------------------------------------------------
extern "C" void kernel_launch(void* const* d_in, const int* in_sizes, int n_in,
                              void* d_out, int out_size, void* d_ws, size_t ws_size,
                              hipStream_t stream) {
    const float* x      = (const float*)d_in[0];   // [B, L, D]
    const float* w_qkv  = (const float*)d_in[1];   // [D, 3D]
    const float* w_proj = (const float*)d_in[2];   // [D, D]
    // d_in[3] num_prefix_tokens: unused — reference mask reduces to pure causal.
    float* out = (float*)d_out;                    // [B, L, D] fp32

    unsigned short* ws     = (unsigned short*)d_ws;
    unsigned short* xb     = ws;                         // 4,194,304
    unsigned short* wqkvT  = xb + 4194304;               // 3,145,728  [3072][1024]
    unsigned short* wprojT = wqkvT + 3145728;            // 1,048,576  [1024][1024]
    unsigned short* qkv    = wprojT + 1048576;           // Q,K [bh][l][d]; V^T [bh][d][l]
    unsigned short* ao     = qkv + 3 * (size_t)SEG;      // 4,194,304

    prep<<<5120, 256, 0, stream>>>(x, w_qkv, w_proj, xb, wqkvT, wprojT);

    gemm_qkv<<<dim3(24, 32), 256, 0, stream>>>(xb, wqkvT, qkv);

    attn_mfma<<<1024, 256, 0, stream>>>(qkv, qkv + SEG, qkv + 2 * (size_t)SEG, ao);

    gemm_proj<<<dim3(16, 64), 256, 0, stream>>>(ao, wprojT, out);
}